// Round 10
// baseline (444.165 us; speedup 1.0000x reference)
//
#include <hip/hip_runtime.h>
#include <hip/hip_bf16.h>

__device__ __forceinline__ float lrelu02(float v) { return v > 0.f ? v : 0.2f * v; }

// manual bf16 <-> f32 (RNE); finite data only
__device__ __forceinline__ float bf2f(unsigned short u) {
    union { unsigned int i; float f; } v; v.i = ((unsigned int)u) << 16; return v.f;
}
__device__ __forceinline__ unsigned short f2bf(float f) {
    union { float f; unsigned int i; } v; v.f = f;
    unsigned int x = v.i;
    return (unsigned short)((x + 0x7fffu + ((x >> 16) & 1u)) >> 16);
}
// packed-pair bf16 extract
__device__ __forceinline__ float blo(unsigned int u) {
    union { unsigned int i; float f; } v; v.i = u << 16; return v.f;
}
__device__ __forceinline__ float bhi(unsigned int u) {
    union { unsigned int i; float f; } v; v.i = u & 0xffff0000u; return v.f;
}

// ---------- fused: CSR rank pass + layer-1 dense (h1 = x @ W1 + attn dots) ----------
// __launch_bounds__(256,4): 4 blocks/CU (32KB LDS) -> ~128 VGPR budget. r9's compiler
// pick of 44 VGPRs register-starved the kernel (no load pipelining; atomics serialized).
__global__ __launch_bounds__(256, 4) void gemm1_k(
    const float* __restrict__ x, const float* __restrict__ W1,
    const float* __restrict__ aw_s, const float* __restrict__ aw_d,
    unsigned short* __restrict__ h1b, float* __restrict__ as1, float* __restrict__ ad1, int N,
    const int* __restrict__ ei, int E, int* __restrict__ deg, int* __restrict__ rank)
{
    // --- rank slice: 5-slot batch -> 5 independent atomic chains in flight ---
    {
        const int total = E + N;
        const int stride = gridDim.x * 256;
        const int e0 = blockIdx.x * 256 + threadIdx.x;
        int dd[5]; bool vv[5];
        #pragma unroll
        for (int i = 0; i < 5; ++i) {
            int e = e0 + i * stride;
            vv[i] = e < total;
            int ec = vv[i] ? e : 0;
            dd[i] = (ec < E) ? ei[E + ec] : (ec - E);   // independent gathers
        }
        int rr[5];
        #pragma unroll
        for (int i = 0; i < 5; ++i)
            if (vv[i]) rr[i] = atomicAdd(&deg[dd[i]], 1);   // independent atomics
        #pragma unroll
        for (int i = 0; i < 5; ++i)
            if (vv[i]) rank[e0 + i * stride] = rr[i];        // coalesced stores
    }

    // --- stage W1 as packed bf16: Wl[k*64 + j] holds cols {2j, 2j+1} of row k ---
    __shared__ unsigned int Wl[128 * 64];   // 32 KB
    {
        const float4* W4 = (const float4*)W1;
        for (int i = threadIdx.x; i < 128 * 32; i += 256) {
            float4 f = W4[i];
            unsigned int lo = f2bf(f.x) | ((unsigned)f2bf(f.y) << 16);
            unsigned int hi = f2bf(f.z) | ((unsigned)f2bf(f.w) << 16);
            int k = i >> 5, t = i & 31;
            Wl[k * 64 + 2 * t]     = lo;
            Wl[k * 64 + 2 * t + 1] = hi;
        }
    }

    const int cl = threadIdx.x & 15;
    const int rg = threadIdx.x >> 4;
    const int head = cl >> 2;
    const int row0 = blockIdx.x * 64 + rg * 4;
    __syncthreads();

    const float4* x4[4];
    bool rv[4];
    #pragma unroll
    for (int r = 0; r < 4; ++r) {
        int rr = row0 + r;
        rv[r] = rr < N;
        int rc = rv[r] ? rr : (N - 1);
        x4[r] = (const float4*)(x + (size_t)rc * 128);
    }

    float acc[4][8];
    #pragma unroll
    for (int r = 0; r < 4; ++r)
        #pragma unroll
        for (int c = 0; c < 8; ++c) acc[r][c] = 0.f;

    for (int k4 = 0; k4 < 32; ++k4) {
        float4 xv[4];
        #pragma unroll
        for (int r = 0; r < 4; ++r) xv[r] = x4[r][k4];
        uint4 wp[4];
        #pragma unroll
        for (int kk = 0; kk < 4; ++kk)
            wp[kk] = *(const uint4*)(Wl + (k4 * 4 + kk) * 64 + cl * 4);   // issue all 4 first
        #pragma unroll
        for (int kk = 0; kk < 4; ++kk) {
            const float w0 = blo(wp[kk].x), w1 = bhi(wp[kk].x);
            const float w2 = blo(wp[kk].y), w3 = bhi(wp[kk].y);
            const float w4 = blo(wp[kk].z), w5 = bhi(wp[kk].z);
            const float w6 = blo(wp[kk].w), w7 = bhi(wp[kk].w);
            #pragma unroll
            for (int r = 0; r < 4; ++r) {
                const float xk = kk == 0 ? xv[r].x : kk == 1 ? xv[r].y : kk == 2 ? xv[r].z : xv[r].w;
                acc[r][0] = fmaf(xk, w0, acc[r][0]);
                acc[r][1] = fmaf(xk, w1, acc[r][1]);
                acc[r][2] = fmaf(xk, w2, acc[r][2]);
                acc[r][3] = fmaf(xk, w3, acc[r][3]);
                acc[r][4] = fmaf(xk, w4, acc[r][4]);
                acc[r][5] = fmaf(xk, w5, acc[r][5]);
                acc[r][6] = fmaf(xk, w6, acc[r][6]);
                acc[r][7] = fmaf(xk, w7, acc[r][7]);
            }
        }
    }

    float ws_[8], wd_[8];
    #pragma unroll
    for (int c = 0; c < 8; ++c) { ws_[c] = aw_s[cl * 8 + c]; wd_[c] = aw_d[cl * 8 + c]; }

    #pragma unroll
    for (int r = 0; r < 4; ++r) {
        float s = 0.f, d = 0.f;
        #pragma unroll
        for (int c = 0; c < 8; ++c) { s = fmaf(acc[r][c], ws_[c], s); d = fmaf(acc[r][c], wd_[c], d); }
        s += __shfl_xor(s, 1); s += __shfl_xor(s, 2);
        d += __shfl_xor(d, 1); d += __shfl_xor(d, 2);
        if (rv[r]) {
            if ((cl & 3) == 0) { as1[(row0 + r) * 4 + head] = s; ad1[(row0 + r) * 4 + head] = d; }
            uint4 pk;
            pk.x = f2bf(acc[r][0]) | ((unsigned)f2bf(acc[r][1]) << 16);
            pk.y = f2bf(acc[r][2]) | ((unsigned)f2bf(acc[r][3]) << 16);
            pk.z = f2bf(acc[r][4]) | ((unsigned)f2bf(acc[r][5]) << 16);
            pk.w = f2bf(acc[r][6]) | ((unsigned)f2bf(acc[r][7]) << 16);
            *(uint4*)(h1b + (size_t)(row0 + r) * 128 + cl * 8) = pk;
        }
    }
}

// ---------- CSR scan ----------
__global__ __launch_bounds__(256) void blocksum_k(
    const int* __restrict__ deg, int N, int* __restrict__ bsum)
{
    __shared__ int sh[256];
    int i = blockIdx.x * 256 + threadIdx.x;
    sh[threadIdx.x] = (i < N) ? deg[i] : 0;
    __syncthreads();
    for (int off = 128; off; off >>= 1) {
        if (threadIdx.x < off) sh[threadIdx.x] += sh[threadIdx.x + off];
        __syncthreads();
    }
    if (threadIdx.x == 0) bsum[blockIdx.x] = sh[0];
}

__global__ __launch_bounds__(1024) void scanbsum_k(int* __restrict__ bsum, int nb)
{
    __shared__ int buf[1024];
    __shared__ int carry;
    if (threadIdx.x == 0) carry = 0;
    __syncthreads();
    for (int base = 0; base < nb; base += 1024) {
        int i = base + threadIdx.x;
        int v = (i < nb) ? bsum[i] : 0;
        buf[threadIdx.x] = v;
        __syncthreads();
        for (int off = 1; off < 1024; off <<= 1) {
            int t = (threadIdx.x >= off) ? buf[threadIdx.x - off] : 0;
            __syncthreads();
            buf[threadIdx.x] += t;
            __syncthreads();
        }
        if (i < nb) bsum[i] = buf[threadIdx.x] - v + carry;   // exclusive
        __syncthreads();
        if (threadIdx.x == 0) carry += buf[1023];
        __syncthreads();
    }
}

__global__ __launch_bounds__(256) void rowptr_k(
    const int* __restrict__ deg, const int* __restrict__ bsum, int N, int E,
    int* __restrict__ rowptr)
{
    __shared__ int buf[256];
    int i = blockIdx.x * 256 + threadIdx.x;
    int v = (i < N) ? deg[i] : 0;
    buf[threadIdx.x] = v;
    __syncthreads();
    for (int off = 1; off < 256; off <<= 1) {
        int t = (threadIdx.x >= off) ? buf[threadIdx.x - off] : 0;
        __syncthreads();
        buf[threadIdx.x] += t;
        __syncthreads();
    }
    if (i < N) rowptr[i] = bsum[blockIdx.x] + buf[threadIdx.x] - v;
    if (i == 0) rowptr[N] = E + N;
}

// Pure scatter, no atomic (rank already known).
__global__ __launch_bounds__(256) void place_k(
    const int* __restrict__ ei, int E, int N,
    const int* __restrict__ rank, const int* __restrict__ rowptr,
    int* __restrict__ csr)
{
    int e = blockIdx.x * 256 + threadIdx.x;
    if (e >= E + N) return;
    int s, d;
    if (e < E) { s = ei[e]; d = ei[E + e]; } else { s = d = e - E; }
    csr[rowptr[d] + rank[e]] = s;
}

// ---------- layer-1 fused: softmax-aggregate + bias + ELU + gemm2 + attn2 dots ----------
__global__ __launch_bounds__(256) void gat1_k(
    const int* __restrict__ csr, const int* __restrict__ rowptr,
    const float* __restrict__ as1, const float* __restrict__ ad1,
    const unsigned short* __restrict__ h1b, const float* __restrict__ b1,
    const float* __restrict__ W2, const float* __restrict__ aw_s2, const float* __restrict__ aw_d2,
    float* __restrict__ g, float* __restrict__ as2, float* __restrict__ ad2, int N)
{
    __shared__ float red[4][8][12];   // [wave][src-lane][j]
    const int wv   = threadIdx.x >> 6;
    const int wid  = (blockIdx.x * 256 + threadIdx.x) >> 6;
    const int lane = threadIdx.x & 63;
    if (wid >= N) return;
    const int start = rowptr[wid], end = rowptr[wid + 1];
    const int i16 = lane & 15;
    const int hh  = lane >> 4;
    const float adh = ad1[wid * 4 + hh];
    const float mh  = lrelu02(as1[wid * 4 + hh] + adh);   // self-logit offset (den >= 1)
    const unsigned short* hb = h1b + lane * 2;

    float den = 0.f, acc0 = 0.f, acc1 = 0.f;
    int k0 = start;
    for (; k0 + 16 <= end; k0 += 16) {
        int s = csr[k0 + i16];
        float w = __expf(lrelu02(as1[s * 4 + hh] + adh) - mh);
        den += w;
        #pragma unroll
        for (int e = 0; e < 16; ++e) {
            int se = __builtin_amdgcn_readlane(s, e);
            float we = __shfl(w, e, 16);
            unsigned int pv = *(const unsigned int*)(hb + (size_t)se * 128);
            acc0 = fmaf(bf2f((unsigned short)pv), we, acc0);
            acc1 = fmaf(bf2f((unsigned short)(pv >> 16)), we, acc1);
        }
    }
    int cnt = end - k0;
    if (cnt > 0) {
        int s = (i16 < cnt) ? csr[k0 + i16] : wid;
        float w = (i16 < cnt) ? __expf(lrelu02(as1[s * 4 + hh] + adh) - mh) : 0.f;
        den += w;
        for (int e = 0; e < cnt; ++e) {
            int se = __builtin_amdgcn_readlane(s, e);
            float we = __shfl(w, e, 16);
            unsigned int pv = *(const unsigned int*)(hb + (size_t)se * 128);
            acc0 = fmaf(bf2f((unsigned short)pv), we, acc0);
            acc1 = fmaf(bf2f((unsigned short)(pv >> 16)), we, acc1);
        }
    }
    den += __shfl_xor(den, 1); den += __shfl_xor(den, 2);
    den += __shfl_xor(den, 4); den += __shfl_xor(den, 8);
    const float rden = 1.f / (den + 1e-16f);
    float v0 = acc0 * rden + b1[lane * 2];
    float v1 = acc1 * rden + b1[lane * 2 + 1];
    v0 = v0 > 0.f ? v0 : expm1f(v0);
    v1 = v1 > 0.f ? v1 : expm1f(v1);

    // --- fused gemm2: g_j = sum_k elu_out[k] * W2[k][j] (k = 2*lane, 2*lane+1) ---
    const float4 a0 = *(const float4*)(W2 + 16 * lane);
    const float4 a1 = *(const float4*)(W2 + 16 * lane + 4);
    const float4 b0 = *(const float4*)(W2 + 16 * lane + 8);
    const float4 b1v = *(const float4*)(W2 + 16 * lane + 12);
    float p[8];
    p[0] = v0 * a0.x + v1 * b0.x;  p[1] = v0 * a0.y + v1 * b0.y;
    p[2] = v0 * a0.z + v1 * b0.z;  p[3] = v0 * a0.w + v1 * b0.w;
    p[4] = v0 * a1.x + v1 * b1v.x; p[5] = v0 * a1.y + v1 * b1v.y;
    p[6] = v0 * a1.z + v1 * b1v.z; p[7] = v0 * a1.w + v1 * b1v.w;
    #pragma unroll
    for (int j = 0; j < 8; ++j) {
        p[j] += __shfl_xor(p[j], 8);
        p[j] += __shfl_xor(p[j], 16);
        p[j] += __shfl_xor(p[j], 32);
    }
    if (lane < 8) {
        #pragma unroll
        for (int j = 0; j < 8; ++j) red[wv][lane][j] = p[j];
    }
    if (lane < 8) {
        float gj = 0.f;
        #pragma unroll
        for (int c = 0; c < 8; ++c) gj += red[wv][c][lane];
        g[(size_t)wid * 8 + lane] = gj;
        float ts = gj * aw_s2[lane], td = gj * aw_d2[lane];
        ts += __shfl_xor(ts, 1); ts += __shfl_xor(ts, 2); ts += __shfl_xor(ts, 4);
        td += __shfl_xor(td, 1); td += __shfl_xor(td, 2); td += __shfl_xor(td, 4);
        if (lane == 0) { as2[wid] = ts; ad2[wid] = td; }
    }
}

// ---------- layer-2 single-pass softmax+aggregate+epilogue: one wave per dst ----------
__global__ __launch_bounds__(256) void gat2_k(
    const int* __restrict__ csr, const int* __restrict__ rowptr,
    const float* __restrict__ as2, const float* __restrict__ ad2,
    const float* __restrict__ g, const float* __restrict__ b2_,
    const float* __restrict__ Wlin, const float* __restrict__ blin,
    float* __restrict__ out, int N)
{
    const int wid  = (blockIdx.x * 256 + threadIdx.x) >> 6;
    const int lane = threadIdx.x & 63;
    if (wid >= N) return;
    const int start = rowptr[wid], end = rowptr[wid + 1];
    const int i8  = lane & 7;
    const int grp = lane >> 3;
    const float adh = ad2[wid];
    const float mh  = lrelu02(as2[wid] + adh);
    float den = 0.f, acc = 0.f;
    int k0 = start;
    for (; k0 + 8 <= end; k0 += 8) {
        int s = csr[k0 + i8];
        float w = __expf(lrelu02(as2[s] + adh) - mh);
        den += w;
        int   se = __shfl(s, grp, 8);
        float we = __shfl(w, grp, 8);
        acc = fmaf(we, g[(size_t)se * 8 + i8], acc);
    }
    int cnt = end - k0;
    if (cnt > 0) {
        int s = (i8 < cnt) ? csr[k0 + i8] : wid;
        float w = (i8 < cnt) ? __expf(lrelu02(as2[s] + adh) - mh) : 0.f;
        den += w;
        int   se = __shfl(s, grp, 8);
        float we = __shfl(w, grp, 8);
        acc = fmaf(we, g[(size_t)se * 8 + i8], acc);
    }
    den += __shfl_xor(den, 1); den += __shfl_xor(den, 2); den += __shfl_xor(den, 4);
    acc += __shfl_xor(acc, 8); acc += __shfl_xor(acc, 16); acc += __shfl_xor(acc, 32);
    float v = acc / (den + 1e-16f) + b2_[i8];
    v = v > 0.f ? v : expm1f(v);
    float t = v * Wlin[i8];
    t += __shfl_xor(t, 1); t += __shfl_xor(t, 2); t += __shfl_xor(t, 4);
    if (lane == 0) out[wid] = 1.f / (1.f + __expf(-(t + blin[0])));
}

extern "C" void kernel_launch(void* const* d_in, const int* in_sizes, int n_in,
                              void* d_out, int out_size, void* d_ws, size_t ws_size,
                              hipStream_t stream)
{
    (void)n_in; (void)out_size; (void)ws_size;
    const float* x    = (const float*)d_in[0];
    const int*   ei   = (const int*)d_in[1];
    // d_in[2] = edge_attr, ignored
    const float* W1   = (const float*)d_in[3];
    const float* as1w = (const float*)d_in[4];
    const float* ad1w = (const float*)d_in[5];
    const float* b1   = (const float*)d_in[6];
    const float* W2   = (const float*)d_in[7];
    const float* as2w = (const float*)d_in[8];
    const float* ad2w = (const float*)d_in[9];
    const float* b2v  = (const float*)d_in[10];
    const float* Wlin = (const float*)d_in[11];
    const float* blin = (const float*)d_in[12];

    const int N = in_sizes[0] / 128;
    const int E = in_sizes[1] / 2;
    const int total = E + N;

    // workspace layout
    float* p = (float*)d_ws;
    unsigned short* h1b = (unsigned short*)p; p += (size_t)N * 64;  // N*128 bf16
    float* as1  = p; p += (size_t)N * 4;
    float* ad1  = p; p += (size_t)N * 4;
    float* g    = p; p += (size_t)N * 8;
    float* as2  = p; p += (size_t)N;
    float* ad2  = p; p += (size_t)N;
    int* deg    = (int*)p; p += (size_t)N;
    int* rowptr = (int*)p; p += (size_t)N + 1;
    int* bsum   = (int*)p; p += ((size_t)N + 255) / 256;
    int* rank   = (int*)p; p += (size_t)total;
    int* csr    = (int*)p; p += (size_t)total;

    const int eb = (total + 255) / 256;
    const int nb = (N + 255) / 256;

    hipMemsetAsync(deg, 0, (size_t)N * sizeof(int), stream);
    // fused: rank pass + layer-1 GEMM (bf16 W in LDS, 32 KB)
    gemm1_k<<<(N + 63) / 64, 256, 0, stream>>>(x, W1, as1w, ad1w, h1b, as1, ad1, N,
                                               ei, E, deg, rank);
    blocksum_k<<<nb, 256, 0, stream>>>(deg, N, bsum);
    scanbsum_k<<<1, 1024, 0, stream>>>(bsum, nb);
    rowptr_k<<<nb, 256, 0, stream>>>(deg, bsum, N, E, rowptr);
    place_k<<<eb, 256, 0, stream>>>(ei, E, N, rank, rowptr, csr);

    // layer 1: softmax + aggregate + bias + ELU + gemm2 + attn2 dots (fused)
    gat1_k<<<(N * 64 + 255) / 256, 256, 0, stream>>>(csr, rowptr, as1, ad1, h1b, b1,
                                                     W2, as2w, ad2w, g, as2, ad2, N);
    // layer 2 + epilogue
    gat2_k<<<(N * 64 + 255) / 256, 256, 0, stream>>>(csr, rowptr, as2, ad2, g, b2v, Wlin, blin,
                                                     (float*)d_out, N);
}